// Round 5
// baseline (136.394 us; speedup 1.0000x reference)
//
#include <hip/hip_runtime.h>

#define HORIZON 10
#define NUM_REGIONS 64
#define BB 32
#define TT 12
#define NN 100000

#define KPW 8                             // 1-KB loads per burst (per wave, per t)
#define NODES_PER_WAVE (KPW * 128)        // 1024
#define NODES_PER_BLOCK (4 * NODES_PER_WAVE)  // 4096 (4 waves/block)

typedef float f32x2 __attribute__((ext_vector_type(2)));
typedef float f32x4 __attribute__((ext_vector_type(4)));
typedef int   i32x2 __attribute__((ext_vector_type(2)));

// Zero gsum/gcount without a rocclr fill kernel.
__global__ __launch_bounds__(256) void init_kernel(float* __restrict__ gsum,
                                                   float* __restrict__ gcount)
{
    const int i = blockIdx.x * 256 + threadIdx.x;
    if (i < BB * NUM_REGIONS) gsum[i] = 0.0f;
    if (i < NUM_REGIONS)      gcount[i] = 0.0f;
}

// Fused main kernel: burst-sequential reads, register t-reduction,
// burst-sequential horizon stores, LDS->global region sums.
__global__ __launch_bounds__(256) void mean_kernel(
    const float* __restrict__ x, const int* __restrict__ cid,
    float* __restrict__ out0, float* __restrict__ gsum)
{
    __shared__ float lsum[NUM_REGIONS];
    const int tid = threadIdx.x;
    if (tid < NUM_REGIONS) lsum[tid] = 0.0f;
    __syncthreads();

    const int b    = blockIdx.y;
    const int wave = tid >> 6;
    const int lane = tid & 63;
    // this wave's node base; instruction k covers nodes base+k*128 .. +127*2
    const int base = blockIdx.x * NODES_PER_BLOCK + wave * NODES_PER_WAVE;

    f32x2 acc[KPW];
    #pragma unroll
    for (int k = 0; k < KPW; ++k) { acc[k].x = 0.0f; acc[k].y = 0.0f; }

    for (int t = 0; t < TT; ++t) {                      // runtime loop: one 8-KB
        const float* xb = x + (size_t)(b * TT + t) * NN * 2;  // sequential burst per t
        #pragma unroll
        for (int k = 0; k < KPW; ++k) {
            const int n0 = base + k * 128 + lane * 2;
            if (n0 < NN) {
                const f32x4 v = *reinterpret_cast<const f32x4*>(xb + (size_t)n0 * 2);
                acc[k].x += v.x;                        // feature 0 of node n0
                acc[k].y += v.z;                        // feature 0 of node n0+1
            }
        }
    }

    const float inv = 1.0f / 12.0f;
    #pragma unroll
    for (int k = 0; k < KPW; ++k) { acc[k].x *= inv; acc[k].y *= inv; }

    float* ob = out0 + (size_t)b * HORIZON * NN;
    for (int h = 0; h < HORIZON; ++h) {                 // burst of 8 stores per h
        #pragma unroll
        for (int k = 0; k < KPW; ++k) {
            const int n0 = base + k * 128 + lane * 2;
            if (n0 < NN)
                *reinterpret_cast<f32x2*>(ob + (size_t)h * NN + n0) = acc[k];
        }
    }

    #pragma unroll
    for (int k = 0; k < KPW; ++k) {
        const int n0 = base + k * 128 + lane * 2;
        if (n0 < NN) {
            const i32x2 c = *reinterpret_cast<const i32x2*>(cid + n0);
            atomicAdd(&lsum[c.x], acc[k].x);
            atomicAdd(&lsum[c.y], acc[k].y);
        }
    }
    __syncthreads();
    if (tid < NUM_REGIONS)
        atomicAdd(&gsum[b * NUM_REGIONS + tid], lsum[tid]);
}

// Region counts.
__global__ __launch_bounds__(256) void count_kernel(
    const int* __restrict__ cid, float* __restrict__ gcount)
{
    __shared__ float lc[NUM_REGIONS];
    const int tid = threadIdx.x;
    if (tid < NUM_REGIONS) lc[tid] = 0.0f;
    __syncthreads();
    const int n = blockIdx.x * 256 + tid;
    if (n < NN) atomicAdd(&lc[cid[n]], 1.0f);
    __syncthreads();
    if (tid < NUM_REGIONS) atomicAdd(&gcount[tid], lc[tid]);
}

// Regional means broadcast over horizon.
__global__ __launch_bounds__(256) void finalize_kernel(
    const float* __restrict__ gsum, const float* __restrict__ gcount,
    float* __restrict__ out1)
{
    const int idx = blockIdx.x * 256 + threadIdx.x;  // 0 .. B*R-1
    if (idx >= BB * NUM_REGIONS) return;
    const int b = idx >> 6;
    const int r = idx & 63;
    const float v = gsum[idx] / gcount[r];
    const size_t base = (size_t)b * HORIZON * NUM_REGIONS + r;
    #pragma unroll
    for (int h = 0; h < HORIZON; ++h) {
        out1[base + (size_t)h * NUM_REGIONS] = v;
    }
}

extern "C" void kernel_launch(void* const* d_in, const int* in_sizes, int n_in,
                              void* d_out, int out_size, void* d_ws, size_t ws_size,
                              hipStream_t stream) {
    const float* x   = (const float*)d_in[0];
    const int*   cid = (const int*)d_in[1];
    float* out0 = (float*)d_out;
    float* out1 = out0 + (size_t)BB * HORIZON * NN;

    float* gsum   = (float*)d_ws;                 // BB*NUM_REGIONS floats
    float* gcount = gsum + BB * NUM_REGIONS;      // NUM_REGIONS floats

    init_kernel<<<(BB * NUM_REGIONS + 255) / 256, 256, 0, stream>>>(gsum, gcount);

    count_kernel<<<(NN + 255) / 256, 256, 0, stream>>>(cid, gcount);

    dim3 gridA((NN + NODES_PER_BLOCK - 1) / NODES_PER_BLOCK, BB);  // (25, 32)
    mean_kernel<<<gridA, 256, 0, stream>>>(x, cid, out0, gsum);

    finalize_kernel<<<(BB * NUM_REGIONS + 255) / 256, 256, 0, stream>>>(
        gsum, gcount, out1);
}

// Round 6
// 96.439 us; speedup vs baseline: 1.4143x; 1.4143x over previous
//
#include <hip/hip_runtime.h>

#define HORIZON 10
#define NUM_REGIONS 64
#define BB 32
#define TT 12
#define NN 100000

typedef float f32x2 __attribute__((ext_vector_type(2)));
typedef float f32x4 __attribute__((ext_vector_type(4)));

// Kernel A (== round-1 structure + nontemporal): per (b, node-pair) —
// time-mean of feature 0, 10 horizon copies, LDS->global region sums.
__global__ __launch_bounds__(256) void mean_kernel(
    const float* __restrict__ x, const int* __restrict__ cid,
    float* __restrict__ out0, float* __restrict__ gsum)
{
    __shared__ float lsum[NUM_REGIONS];
    const int tid = threadIdx.x;
    if (tid < NUM_REGIONS) lsum[tid] = 0.0f;
    __syncthreads();

    const int b = blockIdx.y;
    const int i = blockIdx.x * 256 + tid;   // pair index: nodes 2i, 2i+1
    const int n0 = 2 * i;
    if (n0 < NN) {
        float s0 = 0.0f, s1 = 0.0f;
        #pragma unroll
        for (int t = 0; t < TT; ++t) {
            const f32x4 v = __builtin_nontemporal_load(
                reinterpret_cast<const f32x4*>(
                    x + ((size_t)(b * TT + t) * NN + n0) * 2));
            s0 += v.x;   // feature 0, node n0
            s1 += v.z;   // feature 0, node n0+1
        }
        const float m0 = s0 * (1.0f / 12.0f);
        const float m1 = s1 * (1.0f / 12.0f);
        f32x2 mv; mv.x = m0; mv.y = m1;
        const size_t obase = (size_t)b * HORIZON * NN + n0;
        #pragma unroll
        for (int h = 0; h < HORIZON; ++h) {
            __builtin_nontemporal_store(
                mv, reinterpret_cast<f32x2*>(out0 + obase + (size_t)h * NN));
        }
        atomicAdd(&lsum[cid[n0]], m0);
        atomicAdd(&lsum[cid[n0 + 1]], m1);
    }
    __syncthreads();
    if (tid < NUM_REGIONS) {
        atomicAdd(&gsum[b * NUM_REGIONS + tid], lsum[tid]);
    }
}

// Region counts.
__global__ __launch_bounds__(256) void count_kernel(
    const int* __restrict__ cid, float* __restrict__ gcount)
{
    __shared__ float lc[NUM_REGIONS];
    const int tid = threadIdx.x;
    if (tid < NUM_REGIONS) lc[tid] = 0.0f;
    __syncthreads();
    const int n = blockIdx.x * 256 + tid;
    if (n < NN) atomicAdd(&lc[cid[n]], 1.0f);
    __syncthreads();
    if (tid < NUM_REGIONS) atomicAdd(&gcount[tid], lc[tid]);
}

// Regional means broadcast over horizon.
__global__ __launch_bounds__(256) void finalize_kernel(
    const float* __restrict__ gsum, const float* __restrict__ gcount,
    float* __restrict__ out1)
{
    const int idx = blockIdx.x * 256 + threadIdx.x;  // 0 .. B*R-1
    if (idx >= BB * NUM_REGIONS) return;
    const int b = idx >> 6;
    const int r = idx & 63;
    const float v = gsum[idx] / gcount[r];
    const size_t base = (size_t)b * HORIZON * NUM_REGIONS + r;
    #pragma unroll
    for (int h = 0; h < HORIZON; ++h) {
        out1[base + (size_t)h * NUM_REGIONS] = v;
    }
}

extern "C" void kernel_launch(void* const* d_in, const int* in_sizes, int n_in,
                              void* d_out, int out_size, void* d_ws, size_t ws_size,
                              hipStream_t stream) {
    const float* x   = (const float*)d_in[0];
    const int*   cid = (const int*)d_in[1];
    float* out0 = (float*)d_out;
    float* out1 = out0 + (size_t)BB * HORIZON * NN;

    float* gsum   = (float*)d_ws;                 // BB*NUM_REGIONS floats
    float* gcount = gsum + BB * NUM_REGIONS;      // NUM_REGIONS floats

    (void)hipMemsetAsync(d_ws, 0,
                   (BB * NUM_REGIONS + NUM_REGIONS) * sizeof(float), stream);

    dim3 gridA((NN / 2 + 255) / 256, BB);         // (196, 32)
    mean_kernel<<<gridA, 256, 0, stream>>>(x, cid, out0, gsum);

    count_kernel<<<(NN + 255) / 256, 256, 0, stream>>>(cid, gcount);

    finalize_kernel<<<(BB * NUM_REGIONS + 255) / 256, 256, 0, stream>>>(
        gsum, gcount, out1);
}